// Round 13
// baseline (195.436 us; speedup 1.0000x reference)
//
#include <hip/hip_runtime.h>
#include <hip/hip_fp16.h>

// PillarMaxPooling R13: atomic-RMW -> streaming-store conversion.
// R12's scatter_stats (85us) is bound by 800k random 128B-line atomic RMWs
// (~170MB fabric at ~2TB/s). R13: K1 streams each point's 32-channel h row
// as fp16 (64B sector store, write-only, no RMW) into a bucket arena
// (b = m>>7, slot via padded-cursor atomicAdd: 938 independent lines).
// The 7-bit pillar-local idx rides in the low mantissa bit of channels 0-6
// (error <= ~1e-2, margin 0.0725-0.0156). K2 reads the arena SEQUENTIALLY
// (R11's failure was random gathers; here payload travels with the slot),
// pools in LDS, applies affine+relu, writes every out row once (no out
// memset, no transform). Stats fold unchanged from R12. Arena needs ~62MB
// of d_ws -> runtime fallback to the full R12 path if ws_size too small.
// Named scalars only (local arrays spill on this toolchain, R5-R7).

#define CMLP 32
#define BN_EPS 1e-3f
#define PSIZE 0.075f
#define XMIN -54.0f
#define YMIN -54.0f
#define CZ   -1.0f   // 0.5*(Z_MIN+Z_MAX)
#define NREP 64      // stats replicas
#define SCATB 4096
#define SHIFT 7      // 128 pillars per bucket
#define BCAP 1024    // slots per bucket (mean 853, sigma 29 -> +5.8 sigma)

// ---- ws layout (arena path) ----
#define OFF_STATS 0        // 64 x 64 floats = 16384 B
#define OFF_AFF   16384    // 64 floats
#define OFF_CUR   32768    // 938 cursors, padded to 1/128B line = 120064 B
#define OFF_ARENA 163840   // nbuk * BCAP * 32 ushorts

// monotone float<->uint order map (fallback path)
__device__ __forceinline__ unsigned enc_f(float x) {
  unsigned b = __float_as_uint(x);
  return (b & 0x80000000u) ? ~b : (b | 0x80000000u);
}
__device__ __forceinline__ float dec_f(unsigned u) {
  unsigned b = (u & 0x80000000u) ? (u & 0x7fffffffu) : ~u;
  return __uint_as_float(b);
}

// ============================ arena path ====================================
__global__ void __launch_bounds__(256) k1_arena(
    const float* __restrict__ xyz, const float* __restrict__ ptf,
    const float* __restrict__ W1, const int* __restrict__ pil,
    const int* __restrict__ sidx, float* __restrict__ stats_rep,
    int* __restrict__ cursors, unsigned short* __restrict__ arena, int N) {
  const int tid = threadIdx.x;
  const int c = tid & 31;
  const float w0 = W1[0 * CMLP + c], w1 = W1[1 * CMLP + c];
  const float w2 = W1[2 * CMLP + c], w3 = W1[3 * CMLP + c];
  const float w4 = W1[4 * CMLP + c], w5 = W1[5 * CMLP + c];
  const float w6 = W1[6 * CMLP + c], w7 = W1[7 * CMLP + c];
  const float w8 = W1[8 * CMLP + c], w9 = W1[9 * CMLP + c];
  const float w10 = W1[10 * CMLP + c];
  float s = 0.f, ss = 0.f;
  const int hw0 = (blockIdx.x * 256 + tid) >> 5;
  const int nhw = (SCATB * 256) >> 5;
  const bool leader = (c == 0);    // lane 0 of each half-wave
  const int src = tid & 32;        // shfl source: own half-wave's base lane
  int p = hw0;
  int m = (p < N) ? sidx[p] : 0;
  int slot = 0;
  if (p < N && leader) slot = atomicAdd(&cursors[(m >> SHIFT) * 32], 1);
  slot = __shfl(slot, src);
  while (p < N) {
    const int pn = p + nhw;
    const int mn = (pn < N) ? sidx[pn] : 0;
    int slotn = 0;  // issue next cursor atomic EARLY; consume after compute
    if (pn < N && leader) slotn = atomicAdd(&cursors[(mn >> SHIFT) * 32], 1);
    float cx = fmaf((float)pil[3 * m + 2] + 0.5f, PSIZE, XMIN);
    float cy = fmaf((float)pil[3 * m + 1] + 0.5f, PSIZE, YMIN);
    float x = xyz[3 * p], y = xyz[3 * p + 1], z = xyz[3 * p + 2];
    float h = (x - cx) * w0;
    h = fmaf(y - cy, w1, h);
    h = fmaf(z - CZ, w2, h);
    h = fmaf(x, w3, h);
    h = fmaf(y, w4, h);
    h = fmaf(z, w5, h);
    h = fmaf(ptf[5 * p + 0], w6, h);
    h = fmaf(ptf[5 * p + 1], w7, h);
    h = fmaf(ptf[5 * p + 2], w8, h);
    h = fmaf(ptf[5 * p + 3], w9, h);
    h = fmaf(ptf[5 * p + 4], w10, h);
    s += h;
    ss = fmaf(h, h, ss);
    // fp16 encode; embed pillar-local idx bit k in channel k's low mantissa bit
    unsigned short bits = __half_as_ushort(__float2half_rn(h));
    const int local = m & ((1 << SHIFT) - 1);
    if (c < SHIFT) bits = (unsigned short)((bits & 0xFFFEu) | ((local >> c) & 1));
    if (slot < BCAP)  // 64B sector store, write-only: no RMW
      arena[(size_t)((m >> SHIFT) * BCAP + slot) * 32 + c] = bits;
    slotn = __shfl(slotn, src);
    p = pn;
    m = mn;
    slot = slotn;
  }
  // stats reduce (R12 scheme)
  s += __shfl_xor(s, 32);
  ss += __shfl_xor(ss, 32);
  __shared__ float red[4][64];
  const int wave = tid >> 6, lane = tid & 63;
  if (lane < 32) {
    red[wave][lane] = s;
    red[wave][32 + lane] = ss;
  }
  __syncthreads();
  if (tid < 64) {
    float v = red[0][tid] + red[1][tid] + red[2][tid] + red[3][tid];
    atomicAdd(&stats_rep[(blockIdx.x & (NREP - 1)) * 64 + tid], v);
  }
}

__global__ void __launch_bounds__(256) k2_pool(
    const unsigned short* __restrict__ arena, const int* __restrict__ cursors,
    const float* __restrict__ affine, float* __restrict__ out, int M) {
  __shared__ float acc[128 * CMLP];  // 16 KB
  const int tid = threadIdx.x;
  const int b = blockIdx.x;
  for (int i = tid; i < 128 * CMLP; i += 256) acc[i] = 0.f;
  const int c = tid & 31;
  const float sc = affine[c], bi = affine[CMLP + c];
  __syncthreads();
  const int cnt = min(cursors[b * 32], BCAP);
  const size_t base = (size_t)b * BCAP * 32;
  const int hw = tid >> 5;  // 8 half-waves; half-wave per slot; reads SEQUENTIAL
  for (int kb = 0; kb < cnt; kb += 8) {
    const int k = kb + hw;
    const bool valid = k < cnt;
    unsigned short raw = 0;
    if (valid) raw = arena[base + (size_t)k * 32 + c];
    // reassemble the embedded 7-bit local idx from lanes base..base+6
    unsigned long long mask = __ballot(raw & 1);
    const int local = (int)((mask >> (tid & 32)) & 0x7F);
    if (valid) {
      float h = __half2float(__ushort_as_half(raw));
      float v = fmaxf(fmaf(sc, h, bi), 0.f);  // relu'd -> int order == fp order
      atomicMax((int*)&acc[local * CMLP + c], __float_as_int(v));
    }
  }
  __syncthreads();
  const int mbase = b << SHIFT;  // coalesced writeout; empty pillars stay 0
  for (int i = tid; i < 128 * CMLP; i += 256) {
    if (mbase + (i >> 5) < M) out[(size_t)mbase * CMLP + i] = acc[i];
  }
}

// ========================= shared / fallback ================================
__global__ void finalize_kernel(const float* __restrict__ gamma,
                                const float* __restrict__ beta,
                                const float* __restrict__ stats_rep,
                                float* __restrict__ affine, float invN) {
  int c = threadIdx.x;
  if (c < CMLP) {
    float s = 0.f, ss = 0.f;
    for (int r = 0; r < NREP; r++) {
      s += stats_rep[r * 64 + c];
      ss += stats_rep[r * 64 + 32 + c];
    }
    float mean = s * invN;
    float var = ss * invN - mean * mean;          // biased, like jnp.var
    float sc = gamma[c] * rsqrtf(var + BN_EPS);
    affine[c] = sc;
    affine[CMLP + c] = beta[c] - mean * sc;
  }
}

__global__ void __launch_bounds__(256) scatter_stats_kernel(  // R12 fallback
    const float* __restrict__ xyz, const float* __restrict__ ptf,
    const float* __restrict__ W1, const float* __restrict__ gamma,
    const int* __restrict__ pil, const int* __restrict__ sidx,
    float* __restrict__ stats_rep, unsigned* __restrict__ outenc, int N) {
  const int tid = threadIdx.x;
  const int c = tid & 31;
  const float w0 = W1[0 * CMLP + c], w1 = W1[1 * CMLP + c];
  const float w2 = W1[2 * CMLP + c], w3 = W1[3 * CMLP + c];
  const float w4 = W1[4 * CMLP + c], w5 = W1[5 * CMLP + c];
  const float w6 = W1[6 * CMLP + c], w7 = W1[7 * CMLP + c];
  const float w8 = W1[8 * CMLP + c], w9 = W1[9 * CMLP + c];
  const float w10 = W1[10 * CMLP + c];
  const float sgn = (gamma[c] < 0.f) ? -1.f : 1.f;
  float s = 0.f, ss = 0.f;
  const int hw0 = (blockIdx.x * 256 + tid) >> 5;
  const int nhw = (SCATB * 256) >> 5;
  int p = hw0;
  int m = (p < N) ? sidx[p] : 0;
  while (p < N) {
    const int pn = p + nhw;
    const int mn = (pn < N) ? sidx[pn] : 0;
    float cx = fmaf((float)pil[3 * m + 2] + 0.5f, PSIZE, XMIN);
    float cy = fmaf((float)pil[3 * m + 1] + 0.5f, PSIZE, YMIN);
    float x = xyz[3 * p], y = xyz[3 * p + 1], z = xyz[3 * p + 2];
    float h = (x - cx) * w0;
    h = fmaf(y - cy, w1, h);
    h = fmaf(z - CZ, w2, h);
    h = fmaf(x, w3, h);
    h = fmaf(y, w4, h);
    h = fmaf(z, w5, h);
    h = fmaf(ptf[5 * p + 0], w6, h);
    h = fmaf(ptf[5 * p + 1], w7, h);
    h = fmaf(ptf[5 * p + 2], w8, h);
    h = fmaf(ptf[5 * p + 3], w9, h);
    h = fmaf(ptf[5 * p + 4], w10, h);
    s += h;
    ss = fmaf(h, h, ss);
    unsigned u = enc_f(sgn * h);
    unsigned* addr = &outenc[m * CMLP + c];
    if (u > *addr) atomicMax(addr, u);
    p = pn;
    m = mn;
  }
  s += __shfl_xor(s, 32);
  ss += __shfl_xor(ss, 32);
  __shared__ float red[4][64];
  const int wave = tid >> 6, lane = tid & 63;
  if (lane < 32) {
    red[wave][lane] = s;
    red[wave][32 + lane] = ss;
  }
  __syncthreads();
  if (tid < 64) {
    float v = red[0][tid] + red[1][tid] + red[2][tid] + red[3][tid];
    atomicAdd(&stats_rep[(blockIdx.x & (NREP - 1)) * 64 + tid], v);
  }
}

__global__ void __launch_bounds__(256) transform_kernel(  // R12 fallback
    unsigned* __restrict__ io, const float* __restrict__ affine, int total) {
  int i = blockIdx.x * 256 + threadIdx.x;
  if (i < total) {
    unsigned u = io[i];
    int c = i & 31;
    float v = 0.f;
    if (u) v = fmaxf(fmaf(fabsf(affine[c]), dec_f(u), affine[CMLP + c]), 0.f);
    io[i] = __float_as_uint(v);
  }
}

extern "C" void kernel_launch(void* const* d_in, const int* in_sizes, int n_in,
                              void* d_out, int out_size, void* d_ws, size_t ws_size,
                              hipStream_t stream) {
  const float* xyz = (const float*)d_in[0];
  const float* ptf = (const float*)d_in[1];
  const float* W1 = (const float*)d_in[2];
  const float* gamma = (const float*)d_in[3];
  const float* beta = (const float*)d_in[4];
  const int* pil = (const int*)d_in[5];
  const int* sidx = (const int*)d_in[6];

  int N = in_sizes[0] / 3;
  int M = in_sizes[5] / 3;
  int nbuk = (M + (1 << SHIFT) - 1) >> SHIFT;  // 938

  float* stats_rep = (float*)((char*)d_ws + OFF_STATS);
  float* affine = (float*)((char*)d_ws + OFF_AFF);
  int* cursors = (int*)((char*)d_ws + OFF_CUR);
  unsigned short* arena = (unsigned short*)((char*)d_ws + OFF_ARENA);
  size_t need = (size_t)OFF_ARENA + (size_t)nbuk * BCAP * 32 * sizeof(short);

  if (ws_size >= need) {
    // streaming-arena path
    hipMemsetAsync(d_ws, 0, OFF_ARENA, stream);  // stats + affine + cursors
    k1_arena<<<SCATB, 256, 0, stream>>>(xyz, ptf, W1, pil, sidx, stats_rep,
                                        cursors, arena, N);
    finalize_kernel<<<1, 64, 0, stream>>>(gamma, beta, stats_rep, affine,
                                          1.0f / (float)N);
    k2_pool<<<nbuk, 256, 0, stream>>>(arena, cursors, affine, (float*)d_out, M);
  } else {
    // R12 fallback (measured 171us total)
    unsigned* out = (unsigned*)d_out;
    hipMemsetAsync(stats_rep, 0, NREP * 64 * sizeof(float), stream);
    hipMemsetAsync(out, 0, (size_t)out_size * sizeof(unsigned), stream);
    scatter_stats_kernel<<<SCATB, 256, 0, stream>>>(xyz, ptf, W1, gamma, pil,
                                                    sidx, stats_rep, out, N);
    finalize_kernel<<<1, 64, 0, stream>>>(gamma, beta, stats_rep, affine,
                                          1.0f / (float)N);
    transform_kernel<<<(out_size + 255) / 256, 256, 0, stream>>>(out, affine,
                                                                 out_size);
  }
}

// Round 14
// 173.497 us; speedup vs baseline: 1.1265x; 1.1265x over previous
//
#include <hip/hip_runtime.h>

// PillarMaxPooling R14: revert to R12 (best measured, 171.3us) + filter-value
// prefetch in the scatter loop.
// Ledger: R11 bucket+gather (122us) and R13 streaming arena (117us k1+k2)
// both LOSE to direct atomic scatter (85us) -- the wall is ~800k random-line
// transactions, not RMW-vs-store or byte count. R12 structure: single pass
// computes h per (point,channel); folds BN stats (sum h, sum h^2 -> 64-way
// replicated atomicAdd); scatter-maxes raw sign(gamma)*h (uint monotone
// encode, no stats needed -> single pass); transform applies relu(|sc|e+bi).
// New in R14: prefetch next iteration's outenc filter value (max is monotone
// -> stale filter only causes a redundant atomic) to double the overlap on
// the ~900-cyc random filter-read latency chain.
// Named scalars only (local arrays spill on this toolchain, R5-R7).

#define CMLP 32
#define BN_EPS 1e-3f
#define PSIZE 0.075f
#define XMIN -54.0f
#define YMIN -54.0f
#define CZ   -1.0f   // 0.5*(Z_MIN+Z_MAX)
#define NREP 64      // stats replicas (64 lines apart -> <=64 atomics/address)
#define SCATB 4096

// monotone float<->uint order map; u==0 unreachable from real data
__device__ __forceinline__ unsigned enc_f(float x) {
  unsigned b = __float_as_uint(x);
  return (b & 0x80000000u) ? ~b : (b | 0x80000000u);
}
__device__ __forceinline__ float dec_f(unsigned u) {
  unsigned b = (u & 0x80000000u) ? (u & 0x7fffffffu) : ~u;
  return __uint_as_float(b);
}

__global__ void __launch_bounds__(256) scatter_stats_kernel(
    const float* __restrict__ xyz, const float* __restrict__ ptf,
    const float* __restrict__ W1, const float* __restrict__ gamma,
    const int* __restrict__ pil, const int* __restrict__ sidx,
    float* __restrict__ stats_rep, unsigned* __restrict__ outenc, int N) {
  const int tid = threadIdx.x;
  const int c = tid & 31;
  const float w0 = W1[0 * CMLP + c], w1 = W1[1 * CMLP + c];
  const float w2 = W1[2 * CMLP + c], w3 = W1[3 * CMLP + c];
  const float w4 = W1[4 * CMLP + c], w5 = W1[5 * CMLP + c];
  const float w6 = W1[6 * CMLP + c], w7 = W1[7 * CMLP + c];
  const float w8 = W1[8 * CMLP + c], w9 = W1[9 * CMLP + c];
  const float w10 = W1[10 * CMLP + c];
  const float sgn = (gamma[c] < 0.f) ? -1.f : 1.f;  // sign(sc)=sign(gamma)
  float s = 0.f, ss = 0.f;  // per-channel h moments (this thread's points)
  // half-wave per point; 32 lanes issue the same addresses -> HW broadcast
  const int hw0 = (blockIdx.x * 256 + tid) >> 5;
  const int nhw = (SCATB * 256) >> 5;
  int p = hw0;
  int m = (p < N) ? sidx[p] : 0;
  unsigned* addr = &outenc[m * CMLP + c];
  unsigned old = (p < N) ? *addr : 0u;  // prefetched filter value
  while (p < N) {
    const int pn = p + nhw;
    const int mn = (pn < N) ? sidx[pn] : 0;       // prefetch index
    unsigned* addrn = &outenc[mn * CMLP + c];
    unsigned oldn = (pn < N) ? *addrn : 0u;       // prefetch NEXT filter value
    float cx = fmaf((float)pil[3 * m + 2] + 0.5f, PSIZE, XMIN);
    float cy = fmaf((float)pil[3 * m + 1] + 0.5f, PSIZE, YMIN);
    float x = xyz[3 * p], y = xyz[3 * p + 1], z = xyz[3 * p + 2];
    float h = (x - cx) * w0;
    h = fmaf(y - cy, w1, h);
    h = fmaf(z - CZ, w2, h);
    h = fmaf(x, w3, h);
    h = fmaf(y, w4, h);
    h = fmaf(z, w5, h);
    h = fmaf(ptf[5 * p + 0], w6, h);
    h = fmaf(ptf[5 * p + 1], w7, h);
    h = fmaf(ptf[5 * p + 2], w8, h);
    h = fmaf(ptf[5 * p + 3], w9, h);
    h = fmaf(ptf[5 * p + 4], w10, h);
    s += h;
    ss = fmaf(h, h, ss);
    unsigned u = enc_f(sgn * h);
    // read-filter (prefetched): max monotone -> a stale filter value only
    // causes a redundant atomic, never a wrong skip
    if (u > old) atomicMax(addr, u);
    p = pn;
    m = mn;
    addr = addrn;
    old = oldn;
  }
  // lanes L and L+32 hold the same channel -> combine, stage, block-reduce
  s += __shfl_xor(s, 32);
  ss += __shfl_xor(ss, 32);
  __shared__ float red[4][64];
  const int wave = tid >> 6, lane = tid & 63;
  if (lane < 32) {
    red[wave][lane] = s;
    red[wave][32 + lane] = ss;
  }
  __syncthreads();
  if (tid < 64) {
    float v = red[0][tid] + red[1][tid] + red[2][tid] + red[3][tid];
    // replica blockIdx&63: 64 blocks/address -> no hot-line serialization
    atomicAdd(&stats_rep[(blockIdx.x & (NREP - 1)) * 64 + tid], v);
  }
}

__global__ void finalize_kernel(const float* __restrict__ gamma,
                                const float* __restrict__ beta,
                                const float* __restrict__ stats_rep,
                                float* __restrict__ affine, float invN) {
  int c = threadIdx.x;
  if (c < CMLP) {
    float s = 0.f, ss = 0.f;
    for (int r = 0; r < NREP; r++) {
      s += stats_rep[r * 64 + c];
      ss += stats_rep[r * 64 + 32 + c];
    }
    float mean = s * invN;
    float var = ss * invN - mean * mean;          // biased, like jnp.var
    float sc = gamma[c] * rsqrtf(var + BN_EPS);
    affine[c] = sc;                               // scale
    affine[CMLP + c] = beta[c] - mean * sc;       // bias
  }
}

__global__ void __launch_bounds__(256) transform_kernel(
    unsigned* __restrict__ io, const float* __restrict__ affine, int total) {
  int i = blockIdx.x * 256 + threadIdx.x;
  if (i < total) {
    unsigned u = io[i];
    int c = i & 31;
    float v = 0.f;  // u==0 <=> empty pillar -> 0 (matches max then relu floor)
    if (u) v = fmaxf(fmaf(fabsf(affine[c]), dec_f(u), affine[CMLP + c]), 0.f);
    io[i] = __float_as_uint(v);
  }
}

extern "C" void kernel_launch(void* const* d_in, const int* in_sizes, int n_in,
                              void* d_out, int out_size, void* d_ws, size_t ws_size,
                              hipStream_t stream) {
  const float* xyz = (const float*)d_in[0];
  const float* ptf = (const float*)d_in[1];
  const float* W1 = (const float*)d_in[2];
  const float* gamma = (const float*)d_in[3];
  const float* beta = (const float*)d_in[4];
  const int* pil = (const int*)d_in[5];
  const int* sidx = (const int*)d_in[6];
  unsigned* out = (unsigned*)d_out;

  int N = in_sizes[0] / 3;

  // ws: [0, 16KB) stats replicas (64 x {s[32], ss[32]}); [16KB, +256B) affine
  float* stats_rep = (float*)d_ws;
  float* affine = (float*)((char*)d_ws + NREP * 64 * sizeof(float));

  hipMemsetAsync(stats_rep, 0, NREP * 64 * sizeof(float), stream);
  hipMemsetAsync(out, 0, (size_t)out_size * sizeof(unsigned), stream);

  scatter_stats_kernel<<<SCATB, 256, 0, stream>>>(xyz, ptf, W1, gamma, pil,
                                                  sidx, stats_rep, out, N);
  finalize_kernel<<<1, 64, 0, stream>>>(gamma, beta, stats_rep, affine,
                                        1.0f / (float)N);
  transform_kernel<<<(out_size + 255) / 256, 256, 0, stream>>>(out, affine,
                                                               out_size);
}